// Round 7
// baseline (223.302 us; speedup 1.0000x reference)
//
#include <hip/hip_runtime.h>
#include <cstdint>
#include <cstddef>

#define B_ 8
#define S_ 1024
#define H_ 8
#define D_ 64
#define DM_ 512

typedef __bf16 bf16x8 __attribute__((ext_vector_type(8)));
typedef float floatx4 __attribute__((ext_vector_type(4)));
typedef float floatx16 __attribute__((ext_vector_type(16)));
typedef unsigned short ushort8 __attribute__((ext_vector_type(8)));
typedef unsigned short ushort4v __attribute__((ext_vector_type(4)));
typedef unsigned int uint32x2 __attribute__((ext_vector_type(2)));

union Frag { ushort8 us; bf16x8 bf; };

#define MFMA16(a, b, c) __builtin_amdgcn_mfma_f32_16x16x32_bf16((a), (b), (c), 0, 0, 0)
#define MFMA32(a, b, c) __builtin_amdgcn_mfma_f32_32x32x16_bf16((a), (b), (c), 0, 0, 0)

__device__ __forceinline__ unsigned short f2bf(float f) {
  unsigned int u = __float_as_uint(f);
  unsigned int r = (u + 0x7fffu + ((u >> 16) & 1u)) >> 16;
  return (unsigned short)r;
}

// packed f32x2 -> bf16x2 (RNE, matches f2bf bit-exactly)
__device__ __forceinline__ uint32_t cvtpk_bf16(float lo, float hi) {
  uint32_t r;
  asm("v_cvt_pk_bf16_f32 %0, %1, %2" : "=v"(r) : "v"(lo), "v"(hi));
  return r;
}

// async global->LDS, 16B per lane, LDS dest = wave-uniform base + lane*16
__device__ __forceinline__ void gload16(const void* g, void* l) {
  __builtin_amdgcn_global_load_lds(
      (const __attribute__((address_space(1))) unsigned int*)g,
      (__attribute__((address_space(3))) unsigned int*)l, 16, 0, 0);
}

// ---------------------------------------------------------------------------
// prep, round-7: cast section DELETED (fused into gemm's A-staging).
// [0..383] transpose-cast weights -> wt[3072][512]; [384] zero stats.
// ---------------------------------------------------------------------------
__global__ __launch_bounds__(256) void prep_kernel(
    const float* __restrict__ Wq, const float* __restrict__ Wk,
    const float* __restrict__ Wv, unsigned short* __restrict__ wt,
    float* __restrict__ partial)
{
  __shared__ unsigned short sT[64][72];
  const int tid = threadIdx.x;
  if (blockIdx.x == 384) {
    if (tid < 128) partial[tid] = 0.f;
    return;
  }
  const int bid = blockIdx.x;             // 0..383
  const int k0 = (bid & 7) * 64;
  const int n0 = (bid >> 3) * 64;
  const float* src; int ncols, nb;
  if (n0 < 1536)      { src = Wq; ncols = 1536; nb = n0; }
  else if (n0 < 2560) { src = Wk; ncols = 1024; nb = n0 - 1536; }
  else                { src = Wv; ncols = 512;  nb = n0 - 2560; }

  const int kr0 = tid >> 4, nc4 = (tid & 15) * 4;
  #pragma unroll
  for (int i = 0; i < 4; i++) {
    int kr = kr0 + i * 16;
    floatx4 f = *(const floatx4*)(src + (size_t)(k0 + kr) * ncols + nb + nc4);
    sT[nc4 + 0][kr] = f2bf(f[0]);
    sT[nc4 + 1][kr] = f2bf(f[1]);
    sT[nc4 + 2][kr] = f2bf(f[2]);
    sT[nc4 + 3][kr] = f2bf(f[3]);
  }
  __syncthreads();
  const int nr0 = tid >> 3, kc8 = (tid & 7) * 8;
  #pragma unroll
  for (int i = 0; i < 2; i++) {
    int nr = nr0 + i * 32;
    *(ushort8*)(wt + (size_t)(n0 + nr) * 512 + k0 + kc8) = *(const ushort8*)&sT[nr][kc8];
  }
}

// ---------------------------------------------------------------------------
// Fused projection GEMM, round-7: BK=64 double-buffer (round-3 verified
// pipeline) + FUSED f32->bf16 A-cast (prep's cast section deleted).
// A staged via T14 split: LOADA(kt+1) issues 8 global_load_dwordx4 BEFORE
// COMPUTE(kt) (latency hides under 32 MFMA); after compute, vmcnt(0) +
// 8x f2bf + ds_write_b128 into the idle buffer at the exact slot the old
// gload16 wrote (layout & numerics bit-identical). B stays async gload16.
// q1/q2 pre-scaled by 1/8 * log2(e) so attention uses exp2 directly.
// ---------------------------------------------------------------------------
__global__ __launch_bounds__(256) void gemm_kernel(
    const float* __restrict__ qf, const float* __restrict__ kf,
    const float* __restrict__ vf, const unsigned short* __restrict__ wt,
    const float* __restrict__ bq, const float* __restrict__ bk,
    const float* __restrict__ bv,
    unsigned short* __restrict__ q1, unsigned short* __restrict__ q2,
    float* __restrict__ gate, unsigned short* __restrict__ k1,
    unsigned short* __restrict__ k2, unsigned short* __restrict__ vT)
{
  const int tid  = threadIdx.x;
  const int wave = tid >> 6;
  const int lane = tid & 63;
  const int l16  = lane & 15;
  const int quad = lane >> 4;
  const int mt = blockIdx.x;
  const int nt = blockIdx.y;
  const int wm = wave & 1, wn = wave >> 1;

  const float* Af = (nt < 12) ? qf : (nt < 20) ? kf : vf;

  __shared__ unsigned short sMem[4 * 128 * 64];   // 2 buffers x (sA|sB), 64 KB

  floatx4 acc[4][4];
  #pragma unroll
  for (int i = 0; i < 4; i++)
    #pragma unroll
    for (int j = 0; j < 4; j++)
      #pragma unroll
      for (int r = 0; r < 4; r++) acc[i][j][r] = 0.0f;

  const int lrow   = lane >> 3;
  const int gchunk = (lane & 7) ^ lrow;
  const int rkey   = l16 & 7;

  floatx4 fA[4][2];   // in-flight f32 A data (T14 issue-early)

  auto LOADA = [&](int kt) {
    #pragma unroll
    for (int j = 0; j < 4; j++) {
      int r8 = (wave * 4 + j) * 8;
      const float* ga = Af + (size_t)(mt * 128 + r8 + lrow) * 512 + kt * 64 + gchunk * 8;
      fA[j][0] = *(const floatx4*)ga;
      fA[j][1] = *(const floatx4*)(ga + 4);
    }
  };
  auto WRITEA = [&](int buf) {
    unsigned short* sA = sMem + buf * 16384;
    #pragma unroll
    for (int j = 0; j < 4; j++) {
      ushort8 o;
      o[0] = f2bf(fA[j][0][0]); o[1] = f2bf(fA[j][0][1]);
      o[2] = f2bf(fA[j][0][2]); o[3] = f2bf(fA[j][0][3]);
      o[4] = f2bf(fA[j][1][0]); o[5] = f2bf(fA[j][1][1]);
      o[6] = f2bf(fA[j][1][2]); o[7] = f2bf(fA[j][1][3]);
      *(ushort8*)&sA[(wave * 4 + j) * 512 + lane * 8] = o;
    }
  };
  auto STAGE_B = [&](int kt, int buf) {
    unsigned short* sB = sMem + buf * 16384 + 8192;
    #pragma unroll
    for (int j = 0; j < 4; j++) {
      int r8 = (wave * 4 + j) * 8;
      gload16(wt + (size_t)(nt * 128 + r8 + lrow) * 512 + kt * 64 + gchunk * 8,
              &sB[(wave * 4 + j) * 512]);
    }
  };

  auto COMPUTE = [&](int buf) {
    unsigned short* sA = sMem + buf * 16384;
    unsigned short* sB = sA + 8192;
    #pragma unroll
    for (int c = 0; c < 2; c++) {
      Frag af[4], bf[4];
      #pragma unroll
      for (int mi = 0; mi < 4; mi++)
        af[mi].us = *(const ushort8*)&sA[(wm * 64 + mi * 16 + l16) * 64 +
                                         (((c * 4 + quad) ^ rkey) << 3)];
      #pragma unroll
      for (int ni = 0; ni < 4; ni++)
        bf[ni].us = *(const ushort8*)&sB[(wn * 64 + ni * 16 + l16) * 64 +
                                         (((c * 4 + quad) ^ rkey) << 3)];
      __builtin_amdgcn_s_setprio(1);
      #pragma unroll
      for (int mi = 0; mi < 4; mi++)
        #pragma unroll
        for (int ni = 0; ni < 4; ni++)
          acc[mi][ni] = MFMA16(af[mi].bf, bf[ni].bf, acc[mi][ni]);
      __builtin_amdgcn_s_setprio(0);
    }
  };

  // prologue: fill buffer 0
  LOADA(0);
  STAGE_B(0, 0);
  asm volatile("s_waitcnt vmcnt(0)" ::: "memory");   // fA regs + B gloads done
  WRITEA(0);
  asm volatile("s_waitcnt lgkmcnt(0)" ::: "memory"); // ds_writes drained
  __builtin_amdgcn_s_barrier();

  for (int kt = 0; kt < 8; kt++) {
    if (kt < 7) { LOADA(kt + 1); STAGE_B(kt + 1, (kt + 1) & 1); }  // overlap compute
    COMPUTE(kt & 1);
    if (kt < 7) {
      asm volatile("s_waitcnt vmcnt(0)" ::: "memory");  // fA ready, B landed
      WRITEA((kt + 1) & 1);                             // into idle buffer
    }
    asm volatile("s_waitcnt lgkmcnt(0)" ::: "memory");  // ds reads+writes done
    __builtin_amdgcn_s_barrier();
  }

  const int gm0 = mt * 128 + wm * 64;
  const int bb  = gm0 >> 10;
  const int s0  = gm0 & 1023;
  const int nseg = nt * 2 + wn;
  unsigned short* sC = sMem + wave * 4096;

  int h, sel = 0; bool isV = false;
  const float* bias_arr; int nb0;
  unsigned short* dstb = nullptr;
  if (nseg < 24)      { h = nseg / 3; sel = nseg % 3; bias_arr = bq; nb0 = nseg * 64;
                        dstb = (sel == 0) ? q1 : (sel == 1) ? q2 : nullptr; }
  else if (nseg < 40) { int t = nseg - 24; h = t >> 1; sel = t & 1;
                        bias_arr = bk; nb0 = t * 64; dstb = sel ? k2 : k1; }
  else                { h = nseg - 40; isV = true; bias_arr = bv; nb0 = (nseg - 40) * 64; }

  if (dstb != nullptr || isV) {
    // q-branches: fold 1/sqrt(DK)=1/8 AND log2(e) so attn uses raw v_exp_f32
    const float scl = (nseg < 24) ? 0.125f * 1.44269504088896f : 1.0f;
    #pragma unroll
    for (int ni = 0; ni < 4; ni++) {
      float bv_ = bias_arr[nb0 + ni * 16 + l16];
      #pragma unroll
      for (int mi = 0; mi < 4; mi++)
        #pragma unroll
        for (int r = 0; r < 4; r++) {
          float val = (acc[mi][ni][r] + bv_) * scl;
          int ml = mi * 16 + quad * 4 + r;
          int nl = ni * 16 + l16;
          if (!isV) {
            int ch = (nl >> 3) ^ (ml & 7);
            sC[ml * 64 + (ch << 3) + (nl & 7)] = f2bf(val);
          } else {
            int ch = (ml >> 3) ^ (nl & 7);
            sC[nl * 64 + (ch << 3) + (ml & 7)] = f2bf(val);
          }
        }
    }
    const int rr = lane >> 3, cc = lane & 7;
    if (!isV) {
      unsigned short* base = dstb + ((size_t)(bb * H_ + h) * S_ + s0) * D_;
      #pragma unroll
      for (int j = 0; j < 8; j++) {
        int row = j * 8 + rr;
        int logc = cc ^ (row & 7);
        ushort8 valv = *(const ushort8*)&sC[row * 64 + cc * 8];
        *(ushort8*)(base + (size_t)row * D_ + logc * 8) = valv;
      }
    } else {
      unsigned short* base = vT + ((size_t)(bb * H_ + h) * D_) * S_ + s0;
      #pragma unroll
      for (int j = 0; j < 8; j++) {
        int drow = j * 8 + rr;
        int logc = cc ^ (drow & 7);
        ushort8 valv = *(const ushort8*)&sC[drow * 64 + cc * 8];
        *(ushort8*)(base + (size_t)drow * S_ + logc * 8) = valv;
      }
    }
  } else {
    #pragma unroll
    for (int ni = 0; ni < 4; ni++) {
      float bv_ = bias_arr[nb0 + ni * 16 + l16];
      #pragma unroll
      for (int mi = 0; mi < 4; mi++)
        #pragma unroll
        for (int r = 0; r < 4; r++) {
          int s = s0 + mi * 16 + quad * 4 + r;
          int d = ni * 16 + l16;
          gate[((size_t)(bb * H_ + h) * S_ + s) * D_ + d] = acc[mi][ni][r] + bv_;
        }
    }
  }
}

// ---------------------------------------------------------------------------
// Dual-softmax attention on 32x32x16 MFMA (round-3 verified kernel).
// Wave w=(kh,qh) owns the [kh*32 keys x qh*32 q] S^T tile and the
// [kh*32 d x qh*32 q] O^T tile. global_load_lds staging, raw s_barrier with
// counted vmcnt. STAGE_K(kt) issued BEFORE PV(kt-1); STAGE_V(kt) after
// barrier C. P written as packed b64 quads via v_cvt_pk_bf16_f32; exp via
// exp2 (log2e pre-folded into q-scale). LDS = 40960 B -> 4 blocks/CU.
// ---------------------------------------------------------------------------
__global__ __launch_bounds__(256, 4) void attn_kernel(
    const unsigned short* __restrict__ q1, const unsigned short* __restrict__ q2,
    const unsigned short* __restrict__ k1, const unsigned short* __restrict__ k2,
    const unsigned short* __restrict__ vT, const float* __restrict__ lamp,
    float* __restrict__ O, float* __restrict__ partial)
{
  const int tid   = threadIdx.x;
  const int wave  = tid >> 6;
  const int lane  = tid & 63;
  const int l32   = lane & 31;
  const int lhalf = lane >> 5;
  const int kh    = wave & 1;      // key/d half
  const int qh    = wave >> 1;     // q half
  const int bh = blockIdx.x & 63;
  const int qt = blockIdx.x >> 6;
  const int q0 = qt * 64;

  __shared__ unsigned short sMem[5 * 4096];   // sK1|sK2|sVt|sP1|sP2, 40960 B
  unsigned short* sK1 = sMem;
  unsigned short* sK2 = sMem + 4096;
  unsigned short* sVt = sMem + 8192;
  unsigned short* sP1 = sMem + 12288;
  unsigned short* sP2 = sMem + 16384;

  // Q B-frags: B[k][n]: n=q=qh*32+l32, k=ks*16+lhalf*8+j
  const size_t qrowoff = ((size_t)bh * S_ + q0 + qh * 32 + l32) * D_ + lhalf * 8;
  Frag qb1[4], qb2[4];
  #pragma unroll
  for (int ks = 0; ks < 4; ks++) {
    qb1[ks].us = *(const ushort8*)(q1 + qrowoff + ks * 16);
    qb2[ks].us = *(const ushort8*)(q2 + qrowoff + ks * 16);
  }

  floatx16 o1, o2;
  #pragma unroll
  for (int r = 0; r < 16; r++) { o1[r] = 0.f; o2[r] = 0.f; }
  float l1 = 0.f, l2 = 0.f;

  const unsigned short* kb1 = k1 + (size_t)bh * S_ * D_;
  const unsigned short* kb2 = k2 + (size_t)bh * S_ * D_;
  const unsigned short* vb  = vT + (size_t)bh * D_ * S_;

  const int srow = lane >> 3;          // staging row within 8-row group
  const int sgch = (lane & 7) ^ srow;  // fetched logical chunk (XOR swizzle)
  const int akey = l32 & 7;            // frag-read swizzle key
  const int mrow = kh * 32 + l32;      // this wave's key/d row
  const int qrow = (qh * 32 + l32) * 64;

  auto STAGE_K = [&](int kt) {
    #pragma unroll
    for (int i = 0; i < 2; i++) {
      int r0 = wave * 16 + i * 8;
      gload16(kb1 + (size_t)(kt * 64 + r0 + srow) * 64 + sgch * 8, &sK1[r0 * 64]);
      gload16(kb2 + (size_t)(kt * 64 + r0 + srow) * 64 + sgch * 8, &sK2[r0 * 64]);
    }
  };
  auto STAGE_V = [&](int kt) {
    #pragma unroll
    for (int i = 0; i < 2; i++) {
      int r0 = wave * 16 + i * 8;
      gload16(vb + (size_t)(r0 + srow) * S_ + kt * 64 + sgch * 8, &sVt[r0 * 64]);
    }
  };

  auto S_PHASE = [&]() {
    floatx16 s1, s2;
    #pragma unroll
    for (int r = 0; r < 16; r++) { s1[r] = 0.f; s2[r] = 0.f; }
    __builtin_amdgcn_s_setprio(1);
    #pragma unroll
    for (int ks = 0; ks < 4; ks++) {
      int phys = ((ks * 2 + lhalf) ^ akey) << 3;
      Frag kf1; kf1.us = *(const ushort8*)&sK1[mrow * 64 + phys];
      s1 = MFMA32(kf1.bf, qb1[ks].bf, s1);
      Frag kf2; kf2.us = *(const ushort8*)&sK2[mrow * 64 + phys];
      s2 = MFMA32(kf2.bf, qb2[ks].bf, s2);
    }
    __builtin_amdgcn_s_setprio(0);
    // exp2 + packed b64 P writes: reg quad 4qd..4qd+3 = keys kh*32+8qd+4lhalf+{0..3}
    #pragma unroll
    for (int qd = 0; qd < 4; qd++) {
      const int addr = qrow + (((kh * 4 + qd) ^ akey) << 3) + 4 * lhalf;
      float e0 = __builtin_amdgcn_exp2f(s1[4 * qd + 0]);
      float e1 = __builtin_amdgcn_exp2f(s1[4 * qd + 1]);
      float e2 = __builtin_amdgcn_exp2f(s1[4 * qd + 2]);
      float e3 = __builtin_amdgcn_exp2f(s1[4 * qd + 3]);
      l1 += (e0 + e1) + (e2 + e3);
      uint32x2 w1; w1[0] = cvtpk_bf16(e0, e1); w1[1] = cvtpk_bf16(e2, e3);
      *(uint32x2*)&sP1[addr] = w1;
      float f0 = __builtin_amdgcn_exp2f(s2[4 * qd + 0]);
      float f1 = __builtin_amdgcn_exp2f(s2[4 * qd + 1]);
      float f2 = __builtin_amdgcn_exp2f(s2[4 * qd + 2]);
      float f3 = __builtin_amdgcn_exp2f(s2[4 * qd + 3]);
      l2 += (f0 + f1) + (f2 + f3);
      uint32x2 w2; w2[0] = cvtpk_bf16(f0, f1); w2[1] = cvtpk_bf16(f2, f3);
      *(uint32x2*)&sP2[addr] = w2;
    }
  };

  auto PV_PHASE = [&]() {
    __builtin_amdgcn_s_setprio(1);
    #pragma unroll
    for (int ks = 0; ks < 4; ks++) {
      int phys = ((ks * 2 + lhalf) ^ akey) << 3;
      Frag vf; vf.us = *(const ushort8*)&sVt[mrow * 64 + phys];
      Frag pf1; pf1.us = *(const ushort8*)&sP1[qrow + phys];
      o1 = MFMA32(vf.bf, pf1.bf, o1);
      Frag pf2; pf2.us = *(const ushort8*)&sP2[qrow + phys];
      o2 = MFMA32(vf.bf, pf2.bf, o2);
    }
    __builtin_amdgcn_s_setprio(0);
  };

  // ---- pipelined main loop (PV shifted one tile behind S) ----
  STAGE_K(0);
  STAGE_V(0);
  asm volatile("s_waitcnt vmcnt(2)" ::: "memory");   // K(0) done, V(0) in flight
  __builtin_amdgcn_s_barrier();                      // A(0): sK visible
  S_PHASE();
  asm volatile("s_waitcnt vmcnt(0) lgkmcnt(0)" ::: "memory");  // V(0) + P visible
  __builtin_amdgcn_s_barrier();                      // B(0)

  for (int kt = 1; kt < 16; kt++) {
    STAGE_K(kt);        // sK free since B(kt-1); overlaps PV below
    PV_PHASE();         // reads sVt/sP only
    asm volatile("s_waitcnt lgkmcnt(0)" ::: "memory");  // PV reads done
    __builtin_amdgcn_s_barrier();                       // C: sVt free
    STAGE_V(kt);
    asm volatile("s_waitcnt vmcnt(2)" ::: "memory");    // K(kt) done, V in flight
    __builtin_amdgcn_s_barrier();                       // A: sK visible
    S_PHASE();
    asm volatile("s_waitcnt vmcnt(0) lgkmcnt(0)" ::: "memory");  // V + P visible
    __builtin_amdgcn_s_barrier();                       // B
  }
  PV_PHASE();
  asm volatile("s_waitcnt lgkmcnt(0)" ::: "memory");
  __builtin_amdgcn_s_barrier();

  // ---- epilogue: l reduce, normalize, coalesced O write, fused stats ----
  l1 += __shfl_xor(l1, 32, 64);
  l2 += __shfl_xor(l2, 32, 64);
  float* sL = (float*)(sMem + 10240);   // bytes 20480..21504 (inside dead sVt)
  float* sG = (float*)(sMem + 10752);   // bytes 21504..21568
  if (lane < 32) {
    sL[(0 * 2 + kh) * 64 + qh * 32 + l32] = l1;
    sL[(1 * 2 + kh) * 64 + qh * 32 + l32] = l2;
  }
  __syncthreads();

  const int q = qh * 32 + l32;
  float i1 = 1.0f / (sL[q] + sL[64 + q]);
  float i2 = lamp[0] / (sL[128 + q] + sL[192 + q]);
  float* fO = (float*)sMem;             // bytes 0..16640 (dead sK1/sK2/sVt head)
  #pragma unroll
  for (int r = 0; r < 16; r++) {
    int d = kh * 32 + (r & 3) + 8 * (r >> 2) + 4 * lhalf;
    fO[d * 65 + q] = o1[r] * i1 - o2[r] * i2;
  }
  if (tid < 16) sG[tid] = 0.f;
  __syncthreads();

  float ss = 0.f, ss2 = 0.f;
  float* Ob = O + ((size_t)bh * S_ + q0) * D_;
  #pragma unroll
  for (int i = 0; i < 4; i++) {
    int qrw = i * 16 + (tid >> 4);
    int d0 = (tid & 15) * 4;
    floatx4 v;
    #pragma unroll
    for (int j = 0; j < 4; j++) {
      v[j] = fO[(d0 + j) * 65 + qrw];
      ss += v[j]; ss2 += v[j] * v[j];
    }
    *(floatx4*)(Ob + (size_t)qrw * D_ + d0) = v;
  }
  // reduce lanes sharing the same j-group ((lane&15)>>1)
  ss  += __shfl_xor(ss, 16, 64);  ss  += __shfl_xor(ss, 32, 64);  ss  += __shfl_xor(ss, 1, 64);
  ss2 += __shfl_xor(ss2, 16, 64); ss2 += __shfl_xor(ss2, 32, 64); ss2 += __shfl_xor(ss2, 1, 64);
  if (lane < 16 && (lane & 1) == 0) {
    int j = lane >> 1;
    atomicAdd(&sG[j * 2],     ss);
    atomicAdd(&sG[j * 2 + 1], ss2);
  }
  __syncthreads();
  if (tid < 16) atomicAdd(&partial[(bh >> 3) * 16 + tid], sG[tid]);
}

// ---------------------------------------------------------------------------
// Epilogue, round-5 re-grid: 2048 blocks x 2 x float4 per thread.
// ---------------------------------------------------------------------------
__global__ __launch_bounds__(256) void final_kernel(
    const float* __restrict__ O, const float* __restrict__ gate,
    const float* __restrict__ partial, const float* __restrict__ gamma,
    const float* __restrict__ beta, const float* __restrict__ li,
    float* __restrict__ out)
{
  const int t = blockIdx.x * 256 + threadIdx.x;      // 0..524287
  const float li0 = 1.0f - li[0];
  #pragma unroll
  for (int it = 0; it < 2; it++) {
    int e4 = (it * 524288 + t) * 4;                  // 4-aligned element index
    int d0 = e4 & 63;
    int hh = (e4 >> 6) & 7;
    int s  = (e4 >> 9) & 1023;
    int b  = e4 >> 19;
    size_t oidx = (size_t)(b * 8 + hh) * 65536 + (size_t)s * 64 + d0;
    int g = b * 8 + (d0 >> 3);
    float S1 = partial[g * 2];
    float S2 = partial[g * 2 + 1];
    float mean = S1 * (1.0f / 65536.f);
    float inv  = rsqrtf(S2 * (1.0f / 65536.f) - mean * mean + 0.001f);
    floatx4 o  = *(const floatx4*)(O + oidx);
    floatx4 gt = *(const floatx4*)(gate + oidx);
    floatx4 gm = *(const floatx4*)(gamma + d0);
    floatx4 bt = *(const floatx4*)(beta + d0);
    floatx4 r;
    #pragma unroll
    for (int j = 0; j < 4; j++) {
      float x = (o[j] - mean) * inv;
      x = x * gm[j] + bt[j];
      x *= li0;
      x *= 1.0f / (1.0f + __expf(-gt[j]));
      r[j] = x;
    }
    *(floatx4*)(out + e4) = r;
  }
}

extern "C" void kernel_launch(void* const* d_in, const int* in_sizes, int n_in,
                              void* d_out, int out_size, void* d_ws, size_t ws_size,
                              hipStream_t stream)
{
  const float* query  = (const float*)d_in[0];
  const float* key    = (const float*)d_in[1];
  const float* values = (const float*)d_in[2];
  const float* Wq = (const float*)d_in[3];
  const float* bq = (const float*)d_in[4];
  const float* Wk = (const float*)d_in[5];
  const float* bk = (const float*)d_in[6];
  const float* Wv = (const float*)d_in[7];
  const float* bv = (const float*)d_in[8];
  const float* gamma = (const float*)d_in[9];
  const float* beta  = (const float*)d_in[10];
  const float* lam   = (const float*)d_in[11];
  const float* lami  = (const float*)d_in[12];
  float* out = (float*)d_out;

  char* ws = (char*)d_ws;
  const size_t MB = (size_t)1 << 20;
  float*          O   = (float*)(ws);                     // 16 MB
  unsigned short* wt  = (unsigned short*)(ws + 24 * MB);  // 3 MB
  float* partial      = (float*)(ws + 27 * MB);           // 512 B
  unsigned short* q1  = (unsigned short*)(ws + 28 * MB);
  unsigned short* q2  = (unsigned short*)(ws + 36 * MB);
  unsigned short* k1  = (unsigned short*)(ws + 44 * MB);
  unsigned short* k2  = (unsigned short*)(ws + 52 * MB);
  unsigned short* vT  = (unsigned short*)(ws + 60 * MB);
  float* gate         = (float*)(ws + 68 * MB);           // 16 MB

  prep_kernel<<<385, 256, 0, stream>>>(Wq, Wk, Wv, wt, partial);
  gemm_kernel<<<dim3(64, 24), 256, 0, stream>>>(query, key, values, wt,
                                                bq, bk, bv,
                                                q1, q2, gate, k1, k2, vT);
  attn_kernel<<<dim3(1024), 256, 0, stream>>>(q1, q2, k1, k2, vT, lam, O, partial);
  final_kernel<<<2048, 256, 0, stream>>>(O, gate, partial, gamma, beta, lami, out);
}

// Round 8
// 217.167 us; speedup vs baseline: 1.0282x; 1.0282x over previous
//
#include <hip/hip_runtime.h>
#include <cstdint>
#include <cstddef>

#define B_ 8
#define S_ 1024
#define H_ 8
#define D_ 64
#define DM_ 512

typedef __bf16 bf16x8 __attribute__((ext_vector_type(8)));
typedef float floatx4 __attribute__((ext_vector_type(4)));
typedef float floatx16 __attribute__((ext_vector_type(16)));
typedef unsigned short ushort8 __attribute__((ext_vector_type(8)));
typedef unsigned short ushort4v __attribute__((ext_vector_type(4)));
typedef unsigned int uint32x2 __attribute__((ext_vector_type(2)));

union Frag { ushort8 us; bf16x8 bf; };

#define MFMA16(a, b, c) __builtin_amdgcn_mfma_f32_16x16x32_bf16((a), (b), (c), 0, 0, 0)
#define MFMA32(a, b, c) __builtin_amdgcn_mfma_f32_32x32x16_bf16((a), (b), (c), 0, 0, 0)

__device__ __forceinline__ unsigned short f2bf(float f) {
  unsigned int u = __float_as_uint(f);
  unsigned int r = (u + 0x7fffu + ((u >> 16) & 1u)) >> 16;
  return (unsigned short)r;
}

// packed f32x2 -> bf16x2 (RNE, matches f2bf bit-exactly)
__device__ __forceinline__ uint32_t cvtpk_bf16(float lo, float hi) {
  uint32_t r;
  asm("v_cvt_pk_bf16_f32 %0, %1, %2" : "=v"(r) : "v"(lo), "v"(hi));
  return r;
}

// async global->LDS, 16B per lane, LDS dest = wave-uniform base + lane*16
__device__ __forceinline__ void gload16(const void* g, void* l) {
  __builtin_amdgcn_global_load_lds(
      (const __attribute__((address_space(1))) unsigned int*)g,
      (__attribute__((address_space(3))) unsigned int*)l, 16, 0, 0);
}

// ---------------------------------------------------------------------------
// prep: [0..383] transpose-cast weights -> wt[3072][512]; [384] zero stats.
// ---------------------------------------------------------------------------
__global__ __launch_bounds__(256) void prep_kernel(
    const float* __restrict__ Wq, const float* __restrict__ Wk,
    const float* __restrict__ Wv, unsigned short* __restrict__ wt,
    float* __restrict__ partial)
{
  __shared__ unsigned short sT[64][72];
  const int tid = threadIdx.x;
  if (blockIdx.x == 384) {
    if (tid < 128) partial[tid] = 0.f;
    return;
  }
  const int bid = blockIdx.x;             // 0..383
  const int k0 = (bid & 7) * 64;
  const int n0 = (bid >> 3) * 64;
  const float* src; int ncols, nb;
  if (n0 < 1536)      { src = Wq; ncols = 1536; nb = n0; }
  else if (n0 < 2560) { src = Wk; ncols = 1024; nb = n0 - 1536; }
  else                { src = Wv; ncols = 512;  nb = n0 - 2560; }

  const int kr0 = tid >> 4, nc4 = (tid & 15) * 4;
  #pragma unroll
  for (int i = 0; i < 4; i++) {
    int kr = kr0 + i * 16;
    floatx4 f = *(const floatx4*)(src + (size_t)(k0 + kr) * ncols + nb + nc4);
    sT[nc4 + 0][kr] = f2bf(f[0]);
    sT[nc4 + 1][kr] = f2bf(f[1]);
    sT[nc4 + 2][kr] = f2bf(f[2]);
    sT[nc4 + 3][kr] = f2bf(f[3]);
  }
  __syncthreads();
  const int nr0 = tid >> 3, kc8 = (tid & 7) * 8;
  #pragma unroll
  for (int i = 0; i < 2; i++) {
    int nr = nr0 + i * 32;
    *(ushort8*)(wt + (size_t)(n0 + nr) * 512 + k0 + kc8) = *(const ushort8*)&sT[nr][kc8];
  }
}

// ---------------------------------------------------------------------------
// Fused projection GEMM, round-8: 512 threads / 8 waves per block.
// Same 128x128xBK=64 dbuf (64KB) + counted-vmcnt pipeline + fused f32->bf16
// A-cast, but 2x waves/SIMD (16 waves/CU at 2 blocks/CU) — gemm was
// latency-bound at 2 waves/SIMD (Occupancy 16-18% in every R2..R7 variant
// while MFMA/LDS/HBM all <25%). Wave (wm=w&1, wn=w>>1) owns a 64x32 output
// sub-tile; staging j-loops 4->2; epilogue routed per 32-col half-segment.
// q1/q2 pre-scaled by 1/8 * log2(e) so attention uses exp2 directly.
// ---------------------------------------------------------------------------
__global__ __launch_bounds__(512) void gemm_kernel(
    const float* __restrict__ qf, const float* __restrict__ kf,
    const float* __restrict__ vf, const unsigned short* __restrict__ wt,
    const float* __restrict__ bq, const float* __restrict__ bk,
    const float* __restrict__ bv,
    unsigned short* __restrict__ q1, unsigned short* __restrict__ q2,
    float* __restrict__ gate, unsigned short* __restrict__ k1,
    unsigned short* __restrict__ k2, unsigned short* __restrict__ vT)
{
  const int tid  = threadIdx.x;
  const int wave = tid >> 6;          // 0..7
  const int lane = tid & 63;
  const int l16  = lane & 15;
  const int quad = lane >> 4;
  const int mt = blockIdx.x;
  const int nt = blockIdx.y;
  const int wm = wave & 1;            // M 64-half
  const int wn = wave >> 1;           // N 32-quarter (0..3)

  const float* Af = (nt < 12) ? qf : (nt < 20) ? kf : vf;

  __shared__ unsigned short sMem[4 * 128 * 64];   // 2 buffers x (sA|sB), 64 KB

  floatx4 acc[4][2];
  #pragma unroll
  for (int i = 0; i < 4; i++)
    #pragma unroll
    for (int j = 0; j < 2; j++)
      #pragma unroll
      for (int r = 0; r < 4; r++) acc[i][j][r] = 0.0f;

  const int lrow   = lane >> 3;
  const int gchunk = (lane & 7) ^ lrow;
  const int rkey   = l16 & 7;

  floatx4 fA[2][2];   // in-flight f32 A data (issue-early / write-late)

  auto LOADA = [&](int kt) {
    #pragma unroll
    for (int j = 0; j < 2; j++) {
      int r8 = (wave * 2 + j) * 8;
      const float* ga = Af + (size_t)(mt * 128 + r8 + lrow) * 512 + kt * 64 + gchunk * 8;
      fA[j][0] = *(const floatx4*)ga;
      fA[j][1] = *(const floatx4*)(ga + 4);
    }
  };
  auto WRITEA = [&](int buf) {
    unsigned short* sA = sMem + buf * 16384;
    #pragma unroll
    for (int j = 0; j < 2; j++) {
      ushort8 o;
      o[0] = f2bf(fA[j][0][0]); o[1] = f2bf(fA[j][0][1]);
      o[2] = f2bf(fA[j][0][2]); o[3] = f2bf(fA[j][0][3]);
      o[4] = f2bf(fA[j][1][0]); o[5] = f2bf(fA[j][1][1]);
      o[6] = f2bf(fA[j][1][2]); o[7] = f2bf(fA[j][1][3]);
      *(ushort8*)&sA[(wave * 2 + j) * 512 + lane * 8] = o;
    }
  };
  auto STAGE_B = [&](int kt, int buf) {
    unsigned short* sB = sMem + buf * 16384 + 8192;
    #pragma unroll
    for (int j = 0; j < 2; j++) {
      int r8 = (wave * 2 + j) * 8;
      gload16(wt + (size_t)(nt * 128 + r8 + lrow) * 512 + kt * 64 + gchunk * 8,
              &sB[(wave * 2 + j) * 512]);
    }
  };

  auto COMPUTE = [&](int buf) {
    unsigned short* sA = sMem + buf * 16384;
    unsigned short* sB = sA + 8192;
    #pragma unroll
    for (int c = 0; c < 2; c++) {
      Frag af[4], bf[2];
      #pragma unroll
      for (int mi = 0; mi < 4; mi++)
        af[mi].us = *(const ushort8*)&sA[(wm * 64 + mi * 16 + l16) * 64 +
                                         (((c * 4 + quad) ^ rkey) << 3)];
      #pragma unroll
      for (int ni = 0; ni < 2; ni++)
        bf[ni].us = *(const ushort8*)&sB[(wn * 32 + ni * 16 + l16) * 64 +
                                         (((c * 4 + quad) ^ rkey) << 3)];
      __builtin_amdgcn_s_setprio(1);
      #pragma unroll
      for (int mi = 0; mi < 4; mi++)
        #pragma unroll
        for (int ni = 0; ni < 2; ni++)
          acc[mi][ni] = MFMA16(af[mi].bf, bf[ni].bf, acc[mi][ni]);
      __builtin_amdgcn_s_setprio(0);
    }
  };

  // prologue: fill buffer 0
  LOADA(0);
  STAGE_B(0, 0);
  asm volatile("s_waitcnt vmcnt(0)" ::: "memory");   // fA regs + B gloads done
  WRITEA(0);
  asm volatile("s_waitcnt lgkmcnt(0)" ::: "memory"); // ds_writes drained
  __builtin_amdgcn_s_barrier();

  for (int kt = 0; kt < 8; kt++) {
    if (kt < 7) { LOADA(kt + 1); STAGE_B(kt + 1, (kt + 1) & 1); }  // overlap compute
    COMPUTE(kt & 1);
    if (kt < 7) {
      asm volatile("s_waitcnt vmcnt(0)" ::: "memory");  // fA ready, B landed
      WRITEA((kt + 1) & 1);                             // into idle buffer
    }
    asm volatile("s_waitcnt lgkmcnt(0)" ::: "memory");  // ds reads+writes done
    __builtin_amdgcn_s_barrier();
  }

  const int gm0 = mt * 128 + wm * 64;
  const int bb  = gm0 >> 10;
  const int s0  = gm0 & 1023;
  const int nseg    = nt * 2 + (wn >> 1);    // 64-col segment id (0..47)
  const int halfcol = (wn & 1) * 32;         // this wave's 32-col half
  unsigned short* sC = sMem + wave * 2048;   // per-wave private scratch

  int h, sel = 0; bool isV = false;
  const float* bias_arr; int nb0;
  unsigned short* dstb = nullptr;
  if (nseg < 24)      { h = nseg / 3; sel = nseg % 3; bias_arr = bq;
                        nb0 = nseg * 64 + halfcol;
                        dstb = (sel == 0) ? q1 : (sel == 1) ? q2 : nullptr; }
  else if (nseg < 40) { int t = nseg - 24; h = t >> 1; sel = t & 1;
                        bias_arr = bk; nb0 = t * 64 + halfcol; dstb = sel ? k2 : k1; }
  else                { h = nseg - 40; isV = true; bias_arr = bv;
                        nb0 = (nseg - 40) * 64 + halfcol; }

  if (dstb != nullptr || isV) {
    // q-branches: fold 1/sqrt(DK)=1/8 AND log2(e) so attn uses exp2 directly
    const float scl = (nseg < 24) ? 0.125f * 1.44269504088896f : 1.0f;
    #pragma unroll
    for (int ni = 0; ni < 2; ni++) {
      float bv_ = bias_arr[nb0 + ni * 16 + l16];
      #pragma unroll
      for (int mi = 0; mi < 4; mi++)
        #pragma unroll
        for (int r = 0; r < 4; r++) {
          float val = (acc[mi][ni][r] + bv_) * scl;
          int ml = mi * 16 + quad * 4 + r;       // local row (s or s-col for V)
          int nl = ni * 16 + l16;                // local col 0..31
          if (!isV) {
            // sC[64 rows][32 cols], 4 chunks/row, XOR key = row&3
            int ch = (nl >> 3) ^ (ml & 3);
            sC[ml * 32 + (ch << 3) + (nl & 7)] = f2bf(val);
          } else {
            // sC[32 d-rows][64 s-cols], 8 chunks/row, XOR key = row&7
            int ch = (ml >> 3) ^ (nl & 7);
            sC[nl * 64 + (ch << 3) + (ml & 7)] = f2bf(val);
          }
        }
    }
    if (!isV) {
      const int rr = lane >> 2, cc = lane & 3;
      unsigned short* base = dstb + ((size_t)(bb * H_ + h) * S_ + s0) * D_ + halfcol;
      #pragma unroll
      for (int j = 0; j < 4; j++) {
        int row = j * 16 + rr;
        int logc = cc ^ (row & 3);
        ushort8 valv = *(const ushort8*)&sC[row * 32 + cc * 8];
        *(ushort8*)(base + (size_t)row * D_ + logc * 8) = valv;
      }
    } else {
      const int rr = lane >> 3, cc = lane & 7;
      unsigned short* base = vT + ((size_t)(bb * H_ + h) * D_ + halfcol) * S_ + s0;
      #pragma unroll
      for (int j = 0; j < 4; j++) {
        int drow = j * 8 + rr;                   // local d 0..31
        int logc = cc ^ (drow & 7);
        ushort8 valv = *(const ushort8*)&sC[drow * 64 + cc * 8];
        *(ushort8*)(base + (size_t)drow * S_ + logc * 8) = valv;
      }
    }
  } else {
    #pragma unroll
    for (int ni = 0; ni < 2; ni++) {
      float bv_ = bias_arr[nb0 + ni * 16 + l16];
      #pragma unroll
      for (int mi = 0; mi < 4; mi++)
        #pragma unroll
        for (int r = 0; r < 4; r++) {
          int s = s0 + mi * 16 + quad * 4 + r;
          int d = halfcol + ni * 16 + l16;
          gate[((size_t)(bb * H_ + h) * S_ + s) * D_ + d] = acc[mi][ni][r] + bv_;
        }
    }
  }
}

// ---------------------------------------------------------------------------
// Dual-softmax attention on 32x32x16 MFMA (round-3 verified kernel).
// Wave w=(kh,qh) owns the [kh*32 keys x qh*32 q] S^T tile and the
// [kh*32 d x qh*32 q] O^T tile. global_load_lds staging, raw s_barrier with
// counted vmcnt. STAGE_K(kt) issued BEFORE PV(kt-1); STAGE_V(kt) after
// barrier C. P written as packed b64 quads via v_cvt_pk_bf16_f32; exp via
// exp2 (log2e pre-folded into q-scale). LDS = 40960 B -> 4 blocks/CU.
// ---------------------------------------------------------------------------
__global__ __launch_bounds__(256, 4) void attn_kernel(
    const unsigned short* __restrict__ q1, const unsigned short* __restrict__ q2,
    const unsigned short* __restrict__ k1, const unsigned short* __restrict__ k2,
    const unsigned short* __restrict__ vT, const float* __restrict__ lamp,
    float* __restrict__ O, float* __restrict__ partial)
{
  const int tid   = threadIdx.x;
  const int wave  = tid >> 6;
  const int lane  = tid & 63;
  const int l32   = lane & 31;
  const int lhalf = lane >> 5;
  const int kh    = wave & 1;      // key/d half
  const int qh    = wave >> 1;     // q half
  const int bh = blockIdx.x & 63;
  const int qt = blockIdx.x >> 6;
  const int q0 = qt * 64;

  __shared__ unsigned short sMem[5 * 4096];   // sK1|sK2|sVt|sP1|sP2, 40960 B
  unsigned short* sK1 = sMem;
  unsigned short* sK2 = sMem + 4096;
  unsigned short* sVt = sMem + 8192;
  unsigned short* sP1 = sMem + 12288;
  unsigned short* sP2 = sMem + 16384;

  // Q B-frags: B[k][n]: n=q=qh*32+l32, k=ks*16+lhalf*8+j
  const size_t qrowoff = ((size_t)bh * S_ + q0 + qh * 32 + l32) * D_ + lhalf * 8;
  Frag qb1[4], qb2[4];
  #pragma unroll
  for (int ks = 0; ks < 4; ks++) {
    qb1[ks].us = *(const ushort8*)(q1 + qrowoff + ks * 16);
    qb2[ks].us = *(const ushort8*)(q2 + qrowoff + ks * 16);
  }

  floatx16 o1, o2;
  #pragma unroll
  for (int r = 0; r < 16; r++) { o1[r] = 0.f; o2[r] = 0.f; }
  float l1 = 0.f, l2 = 0.f;

  const unsigned short* kb1 = k1 + (size_t)bh * S_ * D_;
  const unsigned short* kb2 = k2 + (size_t)bh * S_ * D_;
  const unsigned short* vb  = vT + (size_t)bh * D_ * S_;

  const int srow = lane >> 3;          // staging row within 8-row group
  const int sgch = (lane & 7) ^ srow;  // fetched logical chunk (XOR swizzle)
  const int akey = l32 & 7;            // frag-read swizzle key
  const int mrow = kh * 32 + l32;      // this wave's key/d row
  const int qrow = (qh * 32 + l32) * 64;

  auto STAGE_K = [&](int kt) {
    #pragma unroll
    for (int i = 0; i < 2; i++) {
      int r0 = wave * 16 + i * 8;
      gload16(kb1 + (size_t)(kt * 64 + r0 + srow) * 64 + sgch * 8, &sK1[r0 * 64]);
      gload16(kb2 + (size_t)(kt * 64 + r0 + srow) * 64 + sgch * 8, &sK2[r0 * 64]);
    }
  };
  auto STAGE_V = [&](int kt) {
    #pragma unroll
    for (int i = 0; i < 2; i++) {
      int r0 = wave * 16 + i * 8;
      gload16(vb + (size_t)(r0 + srow) * S_ + kt * 64 + sgch * 8, &sVt[r0 * 64]);
    }
  };

  auto S_PHASE = [&]() {
    floatx16 s1, s2;
    #pragma unroll
    for (int r = 0; r < 16; r++) { s1[r] = 0.f; s2[r] = 0.f; }
    __builtin_amdgcn_s_setprio(1);
    #pragma unroll
    for (int ks = 0; ks < 4; ks++) {
      int phys = ((ks * 2 + lhalf) ^ akey) << 3;
      Frag kf1; kf1.us = *(const ushort8*)&sK1[mrow * 64 + phys];
      s1 = MFMA32(kf1.bf, qb1[ks].bf, s1);
      Frag kf2; kf2.us = *(const ushort8*)&sK2[mrow * 64 + phys];
      s2 = MFMA32(kf2.bf, qb2[ks].bf, s2);
    }
    __builtin_amdgcn_s_setprio(0);
    // exp2 + packed b64 P writes: reg quad 4qd..4qd+3 = keys kh*32+8qd+4lhalf+{0..3}
    #pragma unroll
    for (int qd = 0; qd < 4; qd++) {
      const int addr = qrow + (((kh * 4 + qd) ^ akey) << 3) + 4 * lhalf;
      float e0 = __builtin_amdgcn_exp2f(s1[4 * qd + 0]);
      float e1 = __builtin_amdgcn_exp2f(s1[4 * qd + 1]);
      float e2 = __builtin_amdgcn_exp2f(s1[4 * qd + 2]);
      float e3 = __builtin_amdgcn_exp2f(s1[4 * qd + 3]);
      l1 += (e0 + e1) + (e2 + e3);
      uint32x2 w1; w1[0] = cvtpk_bf16(e0, e1); w1[1] = cvtpk_bf16(e2, e3);
      *(uint32x2*)&sP1[addr] = w1;
      float f0 = __builtin_amdgcn_exp2f(s2[4 * qd + 0]);
      float f1 = __builtin_amdgcn_exp2f(s2[4 * qd + 1]);
      float f2 = __builtin_amdgcn_exp2f(s2[4 * qd + 2]);
      float f3 = __builtin_amdgcn_exp2f(s2[4 * qd + 3]);
      l2 += (f0 + f1) + (f2 + f3);
      uint32x2 w2; w2[0] = cvtpk_bf16(f0, f1); w2[1] = cvtpk_bf16(f2, f3);
      *(uint32x2*)&sP2[addr] = w2;
    }
  };

  auto PV_PHASE = [&]() {
    __builtin_amdgcn_s_setprio(1);
    #pragma unroll
    for (int ks = 0; ks < 4; ks++) {
      int phys = ((ks * 2 + lhalf) ^ akey) << 3;
      Frag vf; vf.us = *(const ushort8*)&sVt[mrow * 64 + phys];
      Frag pf1; pf1.us = *(const ushort8*)&sP1[qrow + phys];
      o1 = MFMA32(vf.bf, pf1.bf, o1);
      Frag pf2; pf2.us = *(const ushort8*)&sP2[qrow + phys];
      o2 = MFMA32(vf.bf, pf2.bf, o2);
    }
    __builtin_amdgcn_s_setprio(0);
  };

  // ---- pipelined main loop (PV shifted one tile behind S) ----
  STAGE_K(0);
  STAGE_V(0);
  asm volatile("s_waitcnt vmcnt(2)" ::: "memory");   // K(0) done, V(0) in flight
  __builtin_amdgcn_s_barrier();                      // A(0): sK visible
  S_PHASE();
  asm volatile("s_waitcnt vmcnt(0) lgkmcnt(0)" ::: "memory");  // V(0) + P visible
  __builtin_amdgcn_s_barrier();                      // B(0)

  for (int kt = 1; kt < 16; kt++) {
    STAGE_K(kt);        // sK free since B(kt-1); overlaps PV below
    PV_PHASE();         // reads sVt/sP only
    asm volatile("s_waitcnt lgkmcnt(0)" ::: "memory");  // PV reads done
    __builtin_amdgcn_s_barrier();                       // C: sVt free
    STAGE_V(kt);
    asm volatile("s_waitcnt vmcnt(2)" ::: "memory");    // K(kt) done, V in flight
    __builtin_amdgcn_s_barrier();                       // A: sK visible
    S_PHASE();
    asm volatile("s_waitcnt vmcnt(0) lgkmcnt(0)" ::: "memory");  // V + P visible
    __builtin_amdgcn_s_barrier();                       // B
  }
  PV_PHASE();
  asm volatile("s_waitcnt lgkmcnt(0)" ::: "memory");
  __builtin_amdgcn_s_barrier();

  // ---- epilogue: l reduce, normalize, coalesced O write, fused stats ----
  l1 += __shfl_xor(l1, 32, 64);
  l2 += __shfl_xor(l2, 32, 64);
  float* sL = (float*)(sMem + 10240);   // bytes 20480..21504 (inside dead sVt)
  float* sG = (float*)(sMem + 10752);   // bytes 21504..21568
  if (lane < 32) {
    sL[(0 * 2 + kh) * 64 + qh * 32 + l32] = l1;
    sL[(1 * 2 + kh) * 64 + qh * 32 + l32] = l2;
  }
  __syncthreads();

  const int q = qh * 32 + l32;
  float i1 = 1.0f / (sL[q] + sL[64 + q]);
  float i2 = lamp[0] / (sL[128 + q] + sL[192 + q]);
  float* fO = (float*)sMem;             // bytes 0..16640 (dead sK1/sK2/sVt head)
  #pragma unroll
  for (int r = 0; r < 16; r++) {
    int d = kh * 32 + (r & 3) + 8 * (r >> 2) + 4 * lhalf;
    fO[d * 65 + q] = o1[r] * i1 - o2[r] * i2;
  }
  if (tid < 16) sG[tid] = 0.f;
  __syncthreads();

  float ss = 0.f, ss2 = 0.f;
  float* Ob = O + ((size_t)bh * S_ + q0) * D_;
  #pragma unroll
  for (int i = 0; i < 4; i++) {
    int qrw = i * 16 + (tid >> 4);
    int d0 = (tid & 15) * 4;
    floatx4 v;
    #pragma unroll
    for (int j = 0; j < 4; j++) {
      v[j] = fO[(d0 + j) * 65 + qrw];
      ss += v[j]; ss2 += v[j] * v[j];
    }
    *(floatx4*)(Ob + (size_t)qrw * D_ + d0) = v;
  }
  // reduce lanes sharing the same j-group ((lane&15)>>1)
  ss  += __shfl_xor(ss, 16, 64);  ss  += __shfl_xor(ss, 32, 64);  ss  += __shfl_xor(ss, 1, 64);
  ss2 += __shfl_xor(ss2, 16, 64); ss2 += __shfl_xor(ss2, 32, 64); ss2 += __shfl_xor(ss2, 1, 64);
  if (lane < 16 && (lane & 1) == 0) {
    int j = lane >> 1;
    atomicAdd(&sG[j * 2],     ss);
    atomicAdd(&sG[j * 2 + 1], ss2);
  }
  __syncthreads();
  if (tid < 16) atomicAdd(&partial[(bh >> 3) * 16 + tid], sG[tid]);
}

// ---------------------------------------------------------------------------
// Epilogue: 2048 blocks x 2 x float4 per thread.
// ---------------------------------------------------------------------------
__global__ __launch_bounds__(256) void final_kernel(
    const float* __restrict__ O, const float* __restrict__ gate,
    const float* __restrict__ partial, const float* __restrict__ gamma,
    const float* __restrict__ beta, const float* __restrict__ li,
    float* __restrict__ out)
{
  const int t = blockIdx.x * 256 + threadIdx.x;      // 0..524287
  const float li0 = 1.0f - li[0];
  #pragma unroll
  for (int it = 0; it < 2; it++) {
    int e4 = (it * 524288 + t) * 4;                  // 4-aligned element index
    int d0 = e4 & 63;
    int hh = (e4 >> 6) & 7;
    int s  = (e4 >> 9) & 1023;
    int b  = e4 >> 19;
    size_t oidx = (size_t)(b * 8 + hh) * 65536 + (size_t)s * 64 + d0;
    int g = b * 8 + (d0 >> 3);
    float S1 = partial[g * 2];
    float S2 = partial[g * 2 + 1];
    float mean = S1 * (1.0f / 65536.f);
    float inv  = rsqrtf(S2 * (1.0f / 65536.f) - mean * mean + 0.001f);
    floatx4 o  = *(const floatx4*)(O + oidx);
    floatx4 gt = *(const floatx4*)(gate + oidx);
    floatx4 gm = *(const floatx4*)(gamma + d0);
    floatx4 bt = *(const floatx4*)(beta + d0);
    floatx4 r;
    #pragma unroll
    for (int j = 0; j < 4; j++) {
      float x = (o[j] - mean) * inv;
      x = x * gm[j] + bt[j];
      x *= li0;
      x *= 1.0f / (1.0f + __expf(-gt[j]));
      r[j] = x;
    }
    *(floatx4*)(out + e4) = r;
  }
}

extern "C" void kernel_launch(void* const* d_in, const int* in_sizes, int n_in,
                              void* d_out, int out_size, void* d_ws, size_t ws_size,
                              hipStream_t stream)
{
  const float* query  = (const float*)d_in[0];
  const float* key    = (const float*)d_in[1];
  const float* values = (const float*)d_in[2];
  const float* Wq = (const float*)d_in[3];
  const float* bq = (const float*)d_in[4];
  const float* Wk = (const float*)d_in[5];
  const float* bk = (const float*)d_in[6];
  const float* Wv = (const float*)d_in[7];
  const float* bv = (const float*)d_in[8];
  const float* gamma = (const float*)d_in[9];
  const float* beta  = (const float*)d_in[10];
  const float* lam   = (const float*)d_in[11];
  const float* lami  = (const float*)d_in[12];
  float* out = (float*)d_out;

  char* ws = (char*)d_ws;
  const size_t MB = (size_t)1 << 20;
  float*          O   = (float*)(ws);                     // 16 MB
  unsigned short* wt  = (unsigned short*)(ws + 24 * MB);  // 3 MB
  float* partial      = (float*)(ws + 27 * MB);           // 512 B
  unsigned short* q1  = (unsigned short*)(ws + 28 * MB);
  unsigned short* q2  = (unsigned short*)(ws + 36 * MB);
  unsigned short* k1  = (unsigned short*)(ws + 44 * MB);
  unsigned short* k2  = (unsigned short*)(ws + 52 * MB);
  unsigned short* vT  = (unsigned short*)(ws + 60 * MB);
  float* gate         = (float*)(ws + 68 * MB);           // 16 MB

  prep_kernel<<<385, 256, 0, stream>>>(Wq, Wk, Wv, wt, partial);
  gemm_kernel<<<dim3(64, 24), 512, 0, stream>>>(query, key, values, wt,
                                                bq, bk, bv,
                                                q1, q2, gate, k1, k2, vT);
  attn_kernel<<<dim3(1024), 256, 0, stream>>>(q1, q2, k1, k2, vT, lam, O, partial);
  final_kernel<<<2048, 256, 0, stream>>>(O, gate, partial, gamma, beta, lami, out);
}

// Round 9
// 209.973 us; speedup vs baseline: 1.0635x; 1.0343x over previous
//
#include <hip/hip_runtime.h>
#include <cstdint>
#include <cstddef>

#define B_ 8
#define S_ 1024
#define H_ 8
#define D_ 64
#define DM_ 512

typedef __bf16 bf16x8 __attribute__((ext_vector_type(8)));
typedef float floatx4 __attribute__((ext_vector_type(4)));
typedef float floatx16 __attribute__((ext_vector_type(16)));
typedef unsigned short ushort8 __attribute__((ext_vector_type(8)));
typedef unsigned short ushort4v __attribute__((ext_vector_type(4)));
typedef unsigned int uint32x2 __attribute__((ext_vector_type(2)));

union Frag { ushort8 us; bf16x8 bf; };

#define MFMA16(a, b, c) __builtin_amdgcn_mfma_f32_16x16x32_bf16((a), (b), (c), 0, 0, 0)
#define MFMA32(a, b, c) __builtin_amdgcn_mfma_f32_32x32x16_bf16((a), (b), (c), 0, 0, 0)

__device__ __forceinline__ unsigned short f2bf(float f) {
  unsigned int u = __float_as_uint(f);
  unsigned int r = (u + 0x7fffu + ((u >> 16) & 1u)) >> 16;
  return (unsigned short)r;
}

// packed f32x2 -> bf16x2 (RNE, matches f2bf bit-exactly)
__device__ __forceinline__ uint32_t cvtpk_bf16(float lo, float hi) {
  uint32_t r;
  asm("v_cvt_pk_bf16_f32 %0, %1, %2" : "=v"(r) : "v"(lo), "v"(hi));
  return r;
}

// async global->LDS, 16B per lane, LDS dest = wave-uniform base + lane*16
__device__ __forceinline__ void gload16(const void* g, void* l) {
  __builtin_amdgcn_global_load_lds(
      (const __attribute__((address_space(1))) unsigned int*)g,
      (__attribute__((address_space(3))) unsigned int*)l, 16, 0, 0);
}

// ---------------------------------------------------------------------------
// prep: [0..383] transpose-cast weights -> wt[3072][512]; [384] zero stats.
// ---------------------------------------------------------------------------
__global__ __launch_bounds__(256) void prep_kernel(
    const float* __restrict__ Wq, const float* __restrict__ Wk,
    const float* __restrict__ Wv, unsigned short* __restrict__ wt,
    float* __restrict__ partial)
{
  __shared__ unsigned short sT[64][72];
  const int tid = threadIdx.x;
  if (blockIdx.x == 384) {
    if (tid < 128) partial[tid] = 0.f;
    return;
  }
  const int bid = blockIdx.x;             // 0..383
  const int k0 = (bid & 7) * 64;
  const int n0 = (bid >> 3) * 64;
  const float* src; int ncols, nb;
  if (n0 < 1536)      { src = Wq; ncols = 1536; nb = n0; }
  else if (n0 < 2560) { src = Wk; ncols = 1024; nb = n0 - 1536; }
  else                { src = Wv; ncols = 512;  nb = n0 - 2560; }

  const int kr0 = tid >> 4, nc4 = (tid & 15) * 4;
  #pragma unroll
  for (int i = 0; i < 4; i++) {
    int kr = kr0 + i * 16;
    floatx4 f = *(const floatx4*)(src + (size_t)(k0 + kr) * ncols + nb + nc4);
    sT[nc4 + 0][kr] = f2bf(f[0]);
    sT[nc4 + 1][kr] = f2bf(f[1]);
    sT[nc4 + 2][kr] = f2bf(f[2]);
    sT[nc4 + 3][kr] = f2bf(f[3]);
  }
  __syncthreads();
  const int nr0 = tid >> 3, kc8 = (tid & 7) * 8;
  #pragma unroll
  for (int i = 0; i < 2; i++) {
    int nr = nr0 + i * 32;
    *(ushort8*)(wt + (size_t)(n0 + nr) * 512 + k0 + kc8) = *(const ushort8*)&sT[nr][kc8];
  }
}

// ---------------------------------------------------------------------------
// Fused projection GEMM (round-8 verified): 512 threads / 8 waves per block,
// 128x128xBK=64 dbuf (64KB), counted-vmcnt pipeline, fused f32->bf16 A-cast.
// Wave (wm=w&1, wn=w>>1) owns a 64x32 output sub-tile.
// q1/q2 pre-scaled by 1/8 * log2(e) so attention uses exp2 directly.
// ---------------------------------------------------------------------------
__global__ __launch_bounds__(512) void gemm_kernel(
    const float* __restrict__ qf, const float* __restrict__ kf,
    const float* __restrict__ vf, const unsigned short* __restrict__ wt,
    const float* __restrict__ bq, const float* __restrict__ bk,
    const float* __restrict__ bv,
    unsigned short* __restrict__ q1, unsigned short* __restrict__ q2,
    float* __restrict__ gate, unsigned short* __restrict__ k1,
    unsigned short* __restrict__ k2, unsigned short* __restrict__ vT)
{
  const int tid  = threadIdx.x;
  const int wave = tid >> 6;          // 0..7
  const int lane = tid & 63;
  const int l16  = lane & 15;
  const int quad = lane >> 4;
  const int mt = blockIdx.x;
  const int nt = blockIdx.y;
  const int wm = wave & 1;            // M 64-half
  const int wn = wave >> 1;           // N 32-quarter (0..3)

  const float* Af = (nt < 12) ? qf : (nt < 20) ? kf : vf;

  __shared__ unsigned short sMem[4 * 128 * 64];   // 2 buffers x (sA|sB), 64 KB

  floatx4 acc[4][2];
  #pragma unroll
  for (int i = 0; i < 4; i++)
    #pragma unroll
    for (int j = 0; j < 2; j++)
      #pragma unroll
      for (int r = 0; r < 4; r++) acc[i][j][r] = 0.0f;

  const int lrow   = lane >> 3;
  const int gchunk = (lane & 7) ^ lrow;
  const int rkey   = l16 & 7;

  floatx4 fA[2][2];   // in-flight f32 A data (issue-early / write-late)

  auto LOADA = [&](int kt) {
    #pragma unroll
    for (int j = 0; j < 2; j++) {
      int r8 = (wave * 2 + j) * 8;
      const float* ga = Af + (size_t)(mt * 128 + r8 + lrow) * 512 + kt * 64 + gchunk * 8;
      fA[j][0] = *(const floatx4*)ga;
      fA[j][1] = *(const floatx4*)(ga + 4);
    }
  };
  auto WRITEA = [&](int buf) {
    unsigned short* sA = sMem + buf * 16384;
    #pragma unroll
    for (int j = 0; j < 2; j++) {
      ushort8 o;
      o[0] = f2bf(fA[j][0][0]); o[1] = f2bf(fA[j][0][1]);
      o[2] = f2bf(fA[j][0][2]); o[3] = f2bf(fA[j][0][3]);
      o[4] = f2bf(fA[j][1][0]); o[5] = f2bf(fA[j][1][1]);
      o[6] = f2bf(fA[j][1][2]); o[7] = f2bf(fA[j][1][3]);
      *(ushort8*)&sA[(wave * 2 + j) * 512 + lane * 8] = o;
    }
  };
  auto STAGE_B = [&](int kt, int buf) {
    unsigned short* sB = sMem + buf * 16384 + 8192;
    #pragma unroll
    for (int j = 0; j < 2; j++) {
      int r8 = (wave * 2 + j) * 8;
      gload16(wt + (size_t)(nt * 128 + r8 + lrow) * 512 + kt * 64 + gchunk * 8,
              &sB[(wave * 2 + j) * 512]);
    }
  };

  auto COMPUTE = [&](int buf) {
    unsigned short* sA = sMem + buf * 16384;
    unsigned short* sB = sA + 8192;
    #pragma unroll
    for (int c = 0; c < 2; c++) {
      Frag af[4], bf[2];
      #pragma unroll
      for (int mi = 0; mi < 4; mi++)
        af[mi].us = *(const ushort8*)&sA[(wm * 64 + mi * 16 + l16) * 64 +
                                         (((c * 4 + quad) ^ rkey) << 3)];
      #pragma unroll
      for (int ni = 0; ni < 2; ni++)
        bf[ni].us = *(const ushort8*)&sB[(wn * 32 + ni * 16 + l16) * 64 +
                                         (((c * 4 + quad) ^ rkey) << 3)];
      __builtin_amdgcn_s_setprio(1);
      #pragma unroll
      for (int mi = 0; mi < 4; mi++)
        #pragma unroll
        for (int ni = 0; ni < 2; ni++)
          acc[mi][ni] = MFMA16(af[mi].bf, bf[ni].bf, acc[mi][ni]);
      __builtin_amdgcn_s_setprio(0);
    }
  };

  // prologue: fill buffer 0
  LOADA(0);
  STAGE_B(0, 0);
  asm volatile("s_waitcnt vmcnt(0)" ::: "memory");   // fA regs + B gloads done
  WRITEA(0);
  asm volatile("s_waitcnt lgkmcnt(0)" ::: "memory"); // ds_writes drained
  __builtin_amdgcn_s_barrier();

  for (int kt = 0; kt < 8; kt++) {
    if (kt < 7) { LOADA(kt + 1); STAGE_B(kt + 1, (kt + 1) & 1); }  // overlap compute
    COMPUTE(kt & 1);
    if (kt < 7) {
      asm volatile("s_waitcnt vmcnt(0)" ::: "memory");  // fA ready, B landed
      WRITEA((kt + 1) & 1);                             // into idle buffer
    }
    asm volatile("s_waitcnt lgkmcnt(0)" ::: "memory");  // ds reads+writes done
    __builtin_amdgcn_s_barrier();
  }

  const int gm0 = mt * 128 + wm * 64;
  const int bb  = gm0 >> 10;
  const int s0  = gm0 & 1023;
  const int nseg    = nt * 2 + (wn >> 1);    // 64-col segment id (0..47)
  const int halfcol = (wn & 1) * 32;         // this wave's 32-col half
  unsigned short* sC = sMem + wave * 2048;   // per-wave private scratch

  int h, sel = 0; bool isV = false;
  const float* bias_arr; int nb0;
  unsigned short* dstb = nullptr;
  if (nseg < 24)      { h = nseg / 3; sel = nseg % 3; bias_arr = bq;
                        nb0 = nseg * 64 + halfcol;
                        dstb = (sel == 0) ? q1 : (sel == 1) ? q2 : nullptr; }
  else if (nseg < 40) { int t = nseg - 24; h = t >> 1; sel = t & 1;
                        bias_arr = bk; nb0 = t * 64 + halfcol; dstb = sel ? k2 : k1; }
  else                { h = nseg - 40; isV = true; bias_arr = bv;
                        nb0 = (nseg - 40) * 64 + halfcol; }

  if (dstb != nullptr || isV) {
    // q-branches: fold 1/sqrt(DK)=1/8 AND log2(e) so attn uses exp2 directly
    const float scl = (nseg < 24) ? 0.125f * 1.44269504088896f : 1.0f;
    #pragma unroll
    for (int ni = 0; ni < 2; ni++) {
      float bv_ = bias_arr[nb0 + ni * 16 + l16];
      #pragma unroll
      for (int mi = 0; mi < 4; mi++)
        #pragma unroll
        for (int r = 0; r < 4; r++) {
          float val = (acc[mi][ni][r] + bv_) * scl;
          int ml = mi * 16 + quad * 4 + r;       // local row (s or s-col for V)
          int nl = ni * 16 + l16;                // local col 0..31
          if (!isV) {
            // sC[64 rows][32 cols], 4 chunks/row, XOR key = row&3
            int ch = (nl >> 3) ^ (ml & 3);
            sC[ml * 32 + (ch << 3) + (nl & 7)] = f2bf(val);
          } else {
            // sC[32 d-rows][64 s-cols], 8 chunks/row, XOR key = row&7
            int ch = (ml >> 3) ^ (nl & 7);
            sC[nl * 64 + (ch << 3) + (ml & 7)] = f2bf(val);
          }
        }
    }
    if (!isV) {
      const int rr = lane >> 2, cc = lane & 3;
      unsigned short* base = dstb + ((size_t)(bb * H_ + h) * S_ + s0) * D_ + halfcol;
      #pragma unroll
      for (int j = 0; j < 4; j++) {
        int row = j * 16 + rr;
        int logc = cc ^ (row & 3);
        ushort8 valv = *(const ushort8*)&sC[row * 32 + cc * 8];
        *(ushort8*)(base + (size_t)row * D_ + logc * 8) = valv;
      }
    } else {
      const int rr = lane >> 3, cc = lane & 7;
      unsigned short* base = vT + ((size_t)(bb * H_ + h) * D_ + halfcol) * S_ + s0;
      #pragma unroll
      for (int j = 0; j < 4; j++) {
        int drow = j * 8 + rr;                   // local d 0..31
        int logc = cc ^ (drow & 7);
        ushort8 valv = *(const ushort8*)&sC[drow * 64 + cc * 8];
        *(ushort8*)(base + (size_t)drow * S_ + logc * 8) = valv;
      }
    }
  } else {
    #pragma unroll
    for (int ni = 0; ni < 2; ni++) {
      float bv_ = bias_arr[nb0 + ni * 16 + l16];
      #pragma unroll
      for (int mi = 0; mi < 4; mi++)
        #pragma unroll
        for (int r = 0; r < 4; r++) {
          int s = s0 + mi * 16 + quad * 4 + r;
          int d = halfcol + ni * 16 + l16;
          gate[((size_t)(bb * H_ + h) * S_ + s) * D_ + d] = acc[mi][ni][r] + bv_;
        }
    }
  }
}

// ---------------------------------------------------------------------------
// Dual-softmax attention, round-9: 8 waves / 128 q-rows per block.
// Per-wave math is IDENTICAL to the round-3 verified kernel (wave (kh,qh)
// owns [kh*32 keys x qh*32 q] S^T and [kh*32 d x qh*32 q] O^T; qh now 0..3).
// The sK1/sK2/sVt staging (24KB/tile) is shared by 8 waves instead of 4:
// per-q staging traffic, staging instructions, and K/V L2 re-reads halve
// (512 blocks). sP1/sP2 grow to 128x64 each. LDS = 57344 B -> 2 blocks/CU
// = 16 waves/CU (TLP unchanged). Same 3-barrier counted-vmcnt pipeline;
// each wave stages 8 rows/array (3 gloads/tile, vmcnt(1) for K-done).
// ---------------------------------------------------------------------------
__global__ __launch_bounds__(512, 4) void attn_kernel(
    const unsigned short* __restrict__ q1, const unsigned short* __restrict__ q2,
    const unsigned short* __restrict__ k1, const unsigned short* __restrict__ k2,
    const unsigned short* __restrict__ vT, const float* __restrict__ lamp,
    float* __restrict__ O, float* __restrict__ partial)
{
  const int tid   = threadIdx.x;
  const int wave  = tid >> 6;          // 0..7
  const int lane  = tid & 63;
  const int l32   = lane & 31;
  const int lhalf = lane >> 5;
  const int kh    = wave & 1;          // key/d half
  const int qh    = wave >> 1;         // q quarter (0..3)
  const int bh = blockIdx.x & 63;
  const int qt = blockIdx.x >> 6;      // 0..7
  const int q0 = qt * 128;

  // sK1[64][64] | sK2 | sVt | sP1[128][64] | sP2  = 57344 B
  __shared__ unsigned short sMem[28672];
  unsigned short* sK1 = sMem;              // ushort 0
  unsigned short* sK2 = sMem + 4096;
  unsigned short* sVt = sMem + 8192;
  unsigned short* sP1 = sMem + 12288;      // 8192 ushorts
  unsigned short* sP2 = sMem + 20480;      // 8192 ushorts

  // Q B-frags: B[k][n]: n=q=qh*32+l32, k=ks*16+lhalf*8+j
  const size_t qrowoff = ((size_t)bh * S_ + q0 + qh * 32 + l32) * D_ + lhalf * 8;
  Frag qb1[4], qb2[4];
  #pragma unroll
  for (int ks = 0; ks < 4; ks++) {
    qb1[ks].us = *(const ushort8*)(q1 + qrowoff + ks * 16);
    qb2[ks].us = *(const ushort8*)(q2 + qrowoff + ks * 16);
  }

  floatx16 o1, o2;
  #pragma unroll
  for (int r = 0; r < 16; r++) { o1[r] = 0.f; o2[r] = 0.f; }
  float l1 = 0.f, l2 = 0.f;

  const unsigned short* kb1 = k1 + (size_t)bh * S_ * D_;
  const unsigned short* kb2 = k2 + (size_t)bh * S_ * D_;
  const unsigned short* vb  = vT + (size_t)bh * D_ * S_;

  const int srow = lane >> 3;          // staging row within 8-row group
  const int sgch = (lane & 7) ^ srow;  // fetched logical chunk (XOR swizzle)
  const int akey = l32 & 7;            // frag-read swizzle key
  const int mrow = kh * 32 + l32;      // this wave's key/d row
  const int qrow = (qh * 32 + l32) * 64;   // P row base (q-local 0..127)

  // each wave stages 8 rows of each array: rows wave*8 .. wave*8+7
  const int r0 = wave * 8;
  auto STAGE_K = [&](int kt) {
    gload16(kb1 + (size_t)(kt * 64 + r0 + srow) * 64 + sgch * 8, &sK1[r0 * 64]);
    gload16(kb2 + (size_t)(kt * 64 + r0 + srow) * 64 + sgch * 8, &sK2[r0 * 64]);
  };
  auto STAGE_V = [&](int kt) {
    gload16(vb + (size_t)(r0 + srow) * S_ + kt * 64 + sgch * 8, &sVt[r0 * 64]);
  };

  auto S_PHASE = [&]() {
    floatx16 s1, s2;
    #pragma unroll
    for (int r = 0; r < 16; r++) { s1[r] = 0.f; s2[r] = 0.f; }
    __builtin_amdgcn_s_setprio(1);
    #pragma unroll
    for (int ks = 0; ks < 4; ks++) {
      int phys = ((ks * 2 + lhalf) ^ akey) << 3;
      Frag kf1; kf1.us = *(const ushort8*)&sK1[mrow * 64 + phys];
      s1 = MFMA32(kf1.bf, qb1[ks].bf, s1);
      Frag kf2; kf2.us = *(const ushort8*)&sK2[mrow * 64 + phys];
      s2 = MFMA32(kf2.bf, qb2[ks].bf, s2);
    }
    __builtin_amdgcn_s_setprio(0);
    // exp2 + packed b64 P writes: reg quad 4qd..4qd+3 = keys kh*32+8qd+4lhalf+{0..3}
    #pragma unroll
    for (int qd = 0; qd < 4; qd++) {
      const int addr = qrow + (((kh * 4 + qd) ^ akey) << 3) + 4 * lhalf;
      float e0 = __builtin_amdgcn_exp2f(s1[4 * qd + 0]);
      float e1 = __builtin_amdgcn_exp2f(s1[4 * qd + 1]);
      float e2 = __builtin_amdgcn_exp2f(s1[4 * qd + 2]);
      float e3 = __builtin_amdgcn_exp2f(s1[4 * qd + 3]);
      l1 += (e0 + e1) + (e2 + e3);
      uint32x2 w1; w1[0] = cvtpk_bf16(e0, e1); w1[1] = cvtpk_bf16(e2, e3);
      *(uint32x2*)&sP1[addr] = w1;
      float f0 = __builtin_amdgcn_exp2f(s2[4 * qd + 0]);
      float f1 = __builtin_amdgcn_exp2f(s2[4 * qd + 1]);
      float f2 = __builtin_amdgcn_exp2f(s2[4 * qd + 2]);
      float f3 = __builtin_amdgcn_exp2f(s2[4 * qd + 3]);
      l2 += (f0 + f1) + (f2 + f3);
      uint32x2 w2; w2[0] = cvtpk_bf16(f0, f1); w2[1] = cvtpk_bf16(f2, f3);
      *(uint32x2*)&sP2[addr] = w2;
    }
  };

  auto PV_PHASE = [&]() {
    __builtin_amdgcn_s_setprio(1);
    #pragma unroll
    for (int ks = 0; ks < 4; ks++) {
      int phys = ((ks * 2 + lhalf) ^ akey) << 3;
      Frag vf; vf.us = *(const ushort8*)&sVt[mrow * 64 + phys];
      Frag pf1; pf1.us = *(const ushort8*)&sP1[qrow + phys];
      o1 = MFMA32(vf.bf, pf1.bf, o1);
      Frag pf2; pf2.us = *(const ushort8*)&sP2[qrow + phys];
      o2 = MFMA32(vf.bf, pf2.bf, o2);
    }
    __builtin_amdgcn_s_setprio(0);
  };

  // ---- pipelined main loop (PV shifted one tile behind S) ----
  STAGE_K(0);                           // 2 loads
  STAGE_V(0);                           // 1 load
  asm volatile("s_waitcnt vmcnt(1)" ::: "memory");   // K(0) done, V(0) in flight
  __builtin_amdgcn_s_barrier();                      // A(0): sK visible
  S_PHASE();
  asm volatile("s_waitcnt vmcnt(0) lgkmcnt(0)" ::: "memory");  // V(0) + P visible
  __builtin_amdgcn_s_barrier();                      // B(0)

  for (int kt = 1; kt < 16; kt++) {
    STAGE_K(kt);        // sK free since B(kt-1); overlaps PV below
    PV_PHASE();         // reads sVt/sP only
    asm volatile("s_waitcnt lgkmcnt(0)" ::: "memory");  // PV reads done
    __builtin_amdgcn_s_barrier();                       // C: sVt free
    STAGE_V(kt);
    asm volatile("s_waitcnt vmcnt(1)" ::: "memory");    // K(kt) done, V in flight
    __builtin_amdgcn_s_barrier();                       // A: sK visible
    S_PHASE();
    asm volatile("s_waitcnt vmcnt(0) lgkmcnt(0)" ::: "memory");  // V + P visible
    __builtin_amdgcn_s_barrier();                       // B
  }
  PV_PHASE();
  asm volatile("s_waitcnt lgkmcnt(0)" ::: "memory");
  __builtin_amdgcn_s_barrier();

  // ---- epilogue: l reduce, normalize, coalesced O write, fused stats ----
  l1 += __shfl_xor(l1, 32, 64);
  l2 += __shfl_xor(l2, 32, 64);
  float* sL = (float*)(sMem + 16896);   // bytes 33792..35840 (dead sP1 tail)
  float* sG = (float*)(sMem + 17920);   // bytes 35840..35904
  if (lane < 32) {
    sL[(0 * 2 + kh) * 128 + qh * 32 + l32] = l1;
    sL[(1 * 2 + kh) * 128 + qh * 32 + l32] = l2;
  }
  __syncthreads();

  const int q = qh * 32 + l32;          // 0..127
  float i1 = 1.0f / (sL[q] + sL[128 + q]);
  float i2 = lamp[0] / (sL[256 + q] + sL[384 + q]);
  float* fO = (float*)sMem;             // 64 x 130 floats = 33280 B (dead region)
  #pragma unroll
  for (int r = 0; r < 16; r++) {
    int d = kh * 32 + (r & 3) + 8 * (r >> 2) + 4 * lhalf;
    fO[d * 130 + q] = o1[r] * i1 - o2[r] * i2;
  }
  if (tid < 16) sG[tid] = 0.f;
  __syncthreads();

  float ss = 0.f, ss2 = 0.f;
  float* Ob = O + ((size_t)bh * S_ + q0) * D_;
  #pragma unroll
  for (int i = 0; i < 4; i++) {
    int qrw = i * 32 + (tid >> 4);      // 0..127
    int d0 = (tid & 15) * 4;
    floatx4 v;
    #pragma unroll
    for (int j = 0; j < 4; j++) {
      v[j] = fO[(d0 + j) * 130 + qrw];
      ss += v[j]; ss2 += v[j] * v[j];
    }
    *(floatx4*)(Ob + (size_t)qrw * D_ + d0) = v;
  }
  // reduce lanes sharing the same j-group ((lane&15)>>1)
  ss  += __shfl_xor(ss, 16, 64);  ss  += __shfl_xor(ss, 32, 64);  ss  += __shfl_xor(ss, 1, 64);
  ss2 += __shfl_xor(ss2, 16, 64); ss2 += __shfl_xor(ss2, 32, 64); ss2 += __shfl_xor(ss2, 1, 64);
  if (lane < 16 && (lane & 1) == 0) {
    int j = lane >> 1;
    atomicAdd(&sG[j * 2],     ss);
    atomicAdd(&sG[j * 2 + 1], ss2);
  }
  __syncthreads();
  if (tid < 16) atomicAdd(&partial[(bh >> 3) * 16 + tid], sG[tid]);
}

// ---------------------------------------------------------------------------
// Epilogue: 2048 blocks x 2 x float4 per thread.
// ---------------------------------------------------------------------------
__global__ __launch_bounds__(256) void final_kernel(
    const float* __restrict__ O, const float* __restrict__ gate,
    const float* __restrict__ partial, const float* __restrict__ gamma,
    const float* __restrict__ beta, const float* __restrict__ li,
    float* __restrict__ out)
{
  const int t = blockIdx.x * 256 + threadIdx.x;      // 0..524287
  const float li0 = 1.0f - li[0];
  #pragma unroll
  for (int it = 0; it < 2; it++) {
    int e4 = (it * 524288 + t) * 4;                  // 4-aligned element index
    int d0 = e4 & 63;
    int hh = (e4 >> 6) & 7;
    int s  = (e4 >> 9) & 1023;
    int b  = e4 >> 19;
    size_t oidx = (size_t)(b * 8 + hh) * 65536 + (size_t)s * 64 + d0;
    int g = b * 8 + (d0 >> 3);
    float S1 = partial[g * 2];
    float S2 = partial[g * 2 + 1];
    float mean = S1 * (1.0f / 65536.f);
    float inv  = rsqrtf(S2 * (1.0f / 65536.f) - mean * mean + 0.001f);
    floatx4 o  = *(const floatx4*)(O + oidx);
    floatx4 gt = *(const floatx4*)(gate + oidx);
    floatx4 gm = *(const floatx4*)(gamma + d0);
    floatx4 bt = *(const floatx4*)(beta + d0);
    floatx4 r;
    #pragma unroll
    for (int j = 0; j < 4; j++) {
      float x = (o[j] - mean) * inv;
      x = x * gm[j] + bt[j];
      x *= li0;
      x *= 1.0f / (1.0f + __expf(-gt[j]));
      r[j] = x;
    }
    *(floatx4*)(out + e4) = r;
  }
}

extern "C" void kernel_launch(void* const* d_in, const int* in_sizes, int n_in,
                              void* d_out, int out_size, void* d_ws, size_t ws_size,
                              hipStream_t stream)
{
  const float* query  = (const float*)d_in[0];
  const float* key    = (const float*)d_in[1];
  const float* values = (const float*)d_in[2];
  const float* Wq = (const float*)d_in[3];
  const float* bq = (const float*)d_in[4];
  const float* Wk = (const float*)d_in[5];
  const float* bk = (const float*)d_in[6];
  const float* Wv = (const float*)d_in[7];
  const float* bv = (const float*)d_in[8];
  const float* gamma = (const float*)d_in[9];
  const float* beta  = (const float*)d_in[10];
  const float* lam   = (const float*)d_in[11];
  const float* lami  = (const float*)d_in[12];
  float* out = (float*)d_out;

  char* ws = (char*)d_ws;
  const size_t MB = (size_t)1 << 20;
  float*          O   = (float*)(ws);                     // 16 MB
  unsigned short* wt  = (unsigned short*)(ws + 24 * MB);  // 3 MB
  float* partial      = (float*)(ws + 27 * MB);           // 512 B
  unsigned short* q1  = (unsigned short*)(ws + 28 * MB);
  unsigned short* q2  = (unsigned short*)(ws + 36 * MB);
  unsigned short* k1  = (unsigned short*)(ws + 44 * MB);
  unsigned short* k2  = (unsigned short*)(ws + 52 * MB);
  unsigned short* vT  = (unsigned short*)(ws + 60 * MB);
  float* gate         = (float*)(ws + 68 * MB);           // 16 MB

  prep_kernel<<<385, 256, 0, stream>>>(Wq, Wk, Wv, wt, partial);
  gemm_kernel<<<dim3(64, 24), 512, 0, stream>>>(query, key, values, wt,
                                                bq, bk, bv,
                                                q1, q2, gate, k1, k2, vT);
  attn_kernel<<<dim3(512), 512, 0, stream>>>(q1, q2, k1, k2, vT, lam, O, partial);
  final_kernel<<<2048, 256, 0, stream>>>(O, gate, partial, gamma, beta, lami, out);
}